// Round 1
// baseline (206.583 us; speedup 1.0000x reference)
//
#include <hip/hip_runtime.h>
#include <hip/hip_bf16.h>
#include <math.h>

// Problem constants
#define B_     32
#define C_     512
#define HW_    56
#define PLANE  (HW_*HW_)     // 3136
#define PLANE4 (PLANE/4)     // 784
#define GC_    128
#define WIN_   7
#define POOL_  8
#define L2_    64            // pooled spatial = 8*8
#define HEADS_ 8
#define HD_    64
#define EPS_   1e-5f

// ---------------------------------------------------------------------------
// K1: per-(b,c) plane -> row means (over W) = x_h, col means (over H) = x_w
// ---------------------------------------------------------------------------
__global__ __launch_bounds__(256) void k_means(const float* __restrict__ x,
                                               float* __restrict__ xh,
                                               float* __restrict__ xw) {
    const int bc = blockIdx.x;
    const int t  = threadIdx.x;
    __shared__ float lds[PLANE];
    __shared__ float rp[224];
    __shared__ float cp[224];

    const float4* p4 = (const float4*)(x + (size_t)bc * PLANE);
    for (int f = t; f < PLANE4; f += 256) {
        float4 v = p4[f];
        int base = f * 4;
        lds[base]   = v.x; lds[base+1] = v.y;
        lds[base+2] = v.z; lds[base+3] = v.w;
    }
    __syncthreads();

    if (t < 224) {
        int r = t >> 2, q = t & 3;
        // row partial: row r, quarter q (14 elements)
        float s = 0.f;
        int base = r * HW_ + q * 14;
        #pragma unroll
        for (int i = 0; i < 14; i++) s += lds[base + i];
        rp[t] = s;
        // col partial: col r, quarter q
        float s2 = 0.f;
        int cbase = q * 14 * HW_ + r;
        #pragma unroll
        for (int i = 0; i < 14; i++) s2 += lds[cbase + i * HW_];
        cp[t] = s2;
    }
    __syncthreads();

    if (t < HW_) {
        float rs = rp[4*t] + rp[4*t+1] + rp[4*t+2] + rp[4*t+3];
        xh[(size_t)bc * HW_ + t] = rs * (1.0f / HW_);
        float cs = cp[4*t] + cp[4*t+1] + cp[4*t+2] + cp[4*t+3];
        xw[(size_t)bc * HW_ + t] = cs * (1.0f / HW_);
    }
}

// ---------------------------------------------------------------------------
// K2: per (b, group, {h|w}): depthwise conv1d (k=3/5/7/9) + bias, GroupNorm
// over (128 ch x 56), affine, sigmoid -> gate
// ---------------------------------------------------------------------------
__global__ __launch_bounds__(256) void k_conv_gn_sig(
    const float* __restrict__ xh, const float* __restrict__ xw,
    const float* __restrict__ w3, const float* __restrict__ b3,
    const float* __restrict__ w5, const float* __restrict__ b5,
    const float* __restrict__ w7, const float* __restrict__ b7,
    const float* __restrict__ w9, const float* __restrict__ b9,
    const float* __restrict__ gnh_w, const float* __restrict__ gnh_b,
    const float* __restrict__ gnw_w, const float* __restrict__ gnw_b,
    float* __restrict__ ah, float* __restrict__ aw) {

    const int blk = blockIdx.x;           // B*8
    const int b = blk >> 3;
    const int which = (blk & 7) >> 2;     // 0 = h, 1 = w
    const int g = blk & 3;
    const int t = threadIdx.x;

    const float* in  = (which ? xw : xh) + ((size_t)(b * C_ + g * GC_)) * HW_;
    float*       out = (which ? aw : ah) + ((size_t)(b * C_ + g * GC_)) * HW_;
    const float* gw  = (which ? gnw_w : gnh_w) + g * GC_;
    const float* gb  = (which ? gnw_b : gnh_b) + g * GC_;

    const float* wsel; const float* bsel; int ks;
    switch (g) {
        case 0:  wsel = w3; bsel = b3; ks = 3; break;
        case 1:  wsel = w5; bsel = b5; ks = 5; break;
        case 2:  wsel = w7; bsel = b7; ks = 7; break;
        default: wsel = w9; bsel = b9; ks = 9; break;
    }

    __shared__ float lin[GC_ * HW_];   // 28 KB
    __shared__ float wl[GC_ * 9];
    __shared__ float bl[GC_];
    __shared__ float red[10];

    for (int i = t; i < GC_ * HW_; i += 256) lin[i] = in[i];
    const int nw = GC_ * ks;
    for (int i = t; i < nw; i += 256) wl[i] = wsel[i];
    if (t < GC_) bl[t] = bsel[t];
    __syncthreads();

    const int k2 = ks >> 1;
    float acc[28];
    float s = 0.f, s2 = 0.f;
    #pragma unroll
    for (int k = 0; k < 28; k++) {
        int idx = t + k * 256;
        int c = idx / HW_, l = idx % HW_;
        float a = bl[c];
        for (int tt = 0; tt < ks; tt++) {
            int pos = l + tt - k2;
            if (pos >= 0 && pos < HW_) a += wl[c * ks + tt] * lin[c * HW_ + pos];
        }
        acc[k] = a;
        s += a; s2 += a * a;
    }

    #pragma unroll
    for (int o = 32; o > 0; o >>= 1) { s += __shfl_down(s, o); s2 += __shfl_down(s2, o); }
    int lane = t & 63, wid = t >> 6;
    if (lane == 0) { red[wid] = s; red[4 + wid] = s2; }
    __syncthreads();
    if (t == 0) {
        float S  = red[0] + red[1] + red[2] + red[3];
        float S2 = red[4] + red[5] + red[6] + red[7];
        float mean = S * (1.0f / (GC_ * HW_));
        float var  = S2 * (1.0f / (GC_ * HW_)) - mean * mean;
        red[8] = mean;
        red[9] = rsqrtf(var + EPS_);
    }
    __syncthreads();
    const float mean = red[8], rstd = red[9];

    #pragma unroll
    for (int k = 0; k < 28; k++) {
        int idx = t + k * 256;
        int c = idx / HW_;
        float v = (acc[k] - mean) * rstd * gw[c] + gb[c];
        out[idx] = 1.0f / (1.0f + expf(-v));
    }
}

// ---------------------------------------------------------------------------
// K3: per-(b,c): xg = x * ah[h] * aw[w]; 7x7 avg-pool -> y (B,C,8,8)
// ---------------------------------------------------------------------------
__global__ __launch_bounds__(256) void k_pool(const float* __restrict__ x,
                                              const float* __restrict__ ah,
                                              const float* __restrict__ aw,
                                              float* __restrict__ y) {
    const int bc = blockIdx.x;
    const int t  = threadIdx.x;
    __shared__ float lds[PLANE];
    __shared__ float a_h[HW_];
    __shared__ float a_w[HW_];

    if (t < HW_) {
        a_h[t] = ah[(size_t)bc * HW_ + t];
        a_w[t] = aw[(size_t)bc * HW_ + t];
    }
    __syncthreads();

    const float4* p4 = (const float4*)(x + (size_t)bc * PLANE);
    for (int f = t; f < PLANE4; f += 256) {
        float4 v = p4[f];
        int h = f / 14, jb = (f % 14) * 4;
        float m = a_h[h];
        int base = h * HW_ + jb;
        lds[base]   = v.x * m * a_w[jb];
        lds[base+1] = v.y * m * a_w[jb+1];
        lds[base+2] = v.z * m * a_w[jb+2];
        lds[base+3] = v.w * m * a_w[jb+3];
    }
    __syncthreads();

    if (t < L2_) {
        int hh = t >> 3, ww = t & 7;
        float s = 0.f;
        #pragma unroll
        for (int i = 0; i < WIN_; i++)
            #pragma unroll
            for (int j = 0; j < WIN_; j++)
                s += lds[(WIN_*hh + i) * HW_ + WIN_*ww + j];
        y[(size_t)bc * L2_ + t] = s * (1.0f / (WIN_*WIN_));
    }
}

// ---------------------------------------------------------------------------
// K3.5: per-batch mean/rstd over y[b] (C*64 = 32768 elements)
// ---------------------------------------------------------------------------
__global__ __launch_bounds__(256) void k_ystats(const float* __restrict__ y,
                                                float* __restrict__ stats) {
    const int b = blockIdx.x;
    const int t = threadIdx.x;
    const float* p = y + (size_t)b * (C_ * L2_);
    float s = 0.f, s2 = 0.f;
    for (int i = t; i < C_ * L2_; i += 256) {
        float v = p[i];
        s += v; s2 += v * v;
    }
    __shared__ float red[8];
    #pragma unroll
    for (int o = 32; o > 0; o >>= 1) { s += __shfl_down(s, o); s2 += __shfl_down(s2, o); }
    int lane = t & 63, wid = t >> 6;
    if (lane == 0) { red[wid] = s; red[4 + wid] = s2; }
    __syncthreads();
    if (t == 0) {
        float S  = red[0] + red[1] + red[2] + red[3];
        float S2 = red[4] + red[5] + red[6] + red[7];
        float mean = S * (1.0f / (C_ * L2_));
        float var  = S2 * (1.0f / (C_ * L2_)) - mean * mean;
        stats[b]       = mean;
        stats[B_ + b]  = rsqrtf(var + EPS_);
    }
}

// ---------------------------------------------------------------------------
// K4: per (b, head): y -> GN(affine) -> q,k,v; G = (q k^T)*0.125; softmax rows;
// ca[b, h*64+d] = sigmoid(sum_e p[d,e] * vbar[e]),  vbar[e] = mean_l v[e,l]
// ---------------------------------------------------------------------------
__global__ __launch_bounds__(256) void k_attn(const float* __restrict__ y,
                                              const float* __restrict__ stats,
                                              const float* __restrict__ gn_w,
                                              const float* __restrict__ gn_b,
                                              const float* __restrict__ qw,
                                              const float* __restrict__ kw,
                                              const float* __restrict__ vw,
                                              float* __restrict__ ca) {
    const int blk = blockIdx.x;     // B * HEADS
    const int b = blk >> 3, h = blk & 7;
    const int t = threadIdx.x;

    __shared__ float qs[HD_][68];   // padded: rows 16B-aligned, bank stride 4
    __shared__ float ks_[HD_][68];
    __shared__ float att[HD_][68];  // first holds yn (for vbar), then Gram
    __shared__ float vbar[HD_];

    const float mu = stats[b], rstd = stats[B_ + b];
    const float4* yp4 = (const float4*)(y + ((size_t)(b * C_ + h * HD_)) * L2_);

    for (int f = t; f < 1024; f += 256) {
        int d = f >> 4, lb = (f & 15) << 2;
        int ch = h * HD_ + d;
        float gsc = gn_w[ch] * rstd;
        float gof = gn_b[ch] - mu * gsc;
        float qg = qw[ch], kg = kw[ch];
        float4 v = yp4[f];
        float y0 = v.x * gsc + gof, y1 = v.y * gsc + gof;
        float y2 = v.z * gsc + gof, y3 = v.w * gsc + gof;
        qs[d][lb]   = y0 * qg; qs[d][lb+1] = y1 * qg;
        qs[d][lb+2] = y2 * qg; qs[d][lb+3] = y3 * qg;
        ks_[d][lb]   = y0 * kg; ks_[d][lb+1] = y1 * kg;
        ks_[d][lb+2] = y2 * kg; ks_[d][lb+3] = y3 * kg;
        att[d][lb]   = y0; att[d][lb+1] = y1;
        att[d][lb+2] = y2; att[d][lb+3] = y3;
    }
    __syncthreads();

    if (t < HD_) {
        int ch = h * HD_ + t;
        float s = 0.f;
        #pragma unroll
        for (int l = 0; l < L2_; l++) s += att[t][l];
        vbar[t] = s * (1.0f / L2_) * vw[ch];
    }
    __syncthreads();

    // Gram: thread t -> row d = t>>2, cols e = (t&3) + 4*i, i in [0,16)
    const int d = t >> 2, eb = t & 3;
    float acc[16];
    #pragma unroll
    for (int i = 0; i < 16; i++) acc[i] = 0.f;
    #pragma unroll 4
    for (int lb = 0; lb < 16; lb++) {
        float4 qv = *(const float4*)&qs[d][lb * 4];
        #pragma unroll
        for (int i = 0; i < 16; i++) {
            float4 kv = *(const float4*)&ks_[eb + 4*i][lb * 4];
            acc[i] += qv.x * kv.x + qv.y * kv.y + qv.z * kv.z + qv.w * kv.w;
        }
    }
    __syncthreads();   // everyone done reading att-as-yn? (vbar consumed) and qs/ks
    #pragma unroll
    for (int i = 0; i < 16; i++) att[d][eb + 4*i] = acc[i] * 0.125f;
    __syncthreads();

    // softmax over row d + dot with vbar; 4 threads per row
    {
        float m = -1e30f;
        #pragma unroll
        for (int i = 0; i < 16; i++) m = fmaxf(m, att[d][eb * 16 + i]);
        m = fmaxf(m, __shfl_xor(m, 1));
        m = fmaxf(m, __shfl_xor(m, 2));
        float s1 = 0.f, s2 = 0.f;
        #pragma unroll
        for (int i = 0; i < 16; i++) {
            int e = eb * 16 + i;
            float p = expf(att[d][e] - m);
            s1 += p;
            s2 += p * vbar[e];
        }
        s1 += __shfl_xor(s1, 1); s2 += __shfl_xor(s2, 1);
        s1 += __shfl_xor(s1, 2); s2 += __shfl_xor(s2, 2);
        if (eb == 0) {
            float o = s2 / s1;
            ca[(size_t)b * C_ + h * HD_ + d] = 1.0f / (1.0f + expf(-o));
        }
    }
}

// ---------------------------------------------------------------------------
// K5: out = x * ah[h] * aw[w] * ca[b,c]
// ---------------------------------------------------------------------------
__global__ __launch_bounds__(256) void k_out(const float* __restrict__ x,
                                             const float* __restrict__ ah,
                                             const float* __restrict__ aw,
                                             const float* __restrict__ ca,
                                             float* __restrict__ out) {
    const int bc = blockIdx.x;
    const int t  = threadIdx.x;
    __shared__ float a_h[HW_];
    __shared__ float a_w[HW_];
    if (t < HW_) {
        a_h[t] = ah[(size_t)bc * HW_ + t];
        a_w[t] = aw[(size_t)bc * HW_ + t];
    }
    __syncthreads();
    const float cav = ca[bc];
    const float4* px = (const float4*)(x + (size_t)bc * PLANE);
    float4*       po = (float4*)(out + (size_t)bc * PLANE);
    for (int f = t; f < PLANE4; f += 256) {
        float4 v = px[f];
        int hh = f / 14, jb = (f % 14) * 4;
        float m = cav * a_h[hh];
        v.x *= m * a_w[jb];
        v.y *= m * a_w[jb+1];
        v.z *= m * a_w[jb+2];
        v.w *= m * a_w[jb+3];
        po[f] = v;
    }
}

// ---------------------------------------------------------------------------
extern "C" void kernel_launch(void* const* d_in, const int* in_sizes, int n_in,
                              void* d_out, int out_size, void* d_ws, size_t ws_size,
                              hipStream_t stream) {
    const float* x     = (const float*)d_in[0];
    const float* w3    = (const float*)d_in[1];
    const float* b3    = (const float*)d_in[2];
    const float* w5    = (const float*)d_in[3];
    const float* b5    = (const float*)d_in[4];
    const float* w7    = (const float*)d_in[5];
    const float* b7    = (const float*)d_in[6];
    const float* w9    = (const float*)d_in[7];
    const float* b9    = (const float*)d_in[8];
    const float* gnh_w = (const float*)d_in[9];
    const float* gnh_b = (const float*)d_in[10];
    const float* gnw_w = (const float*)d_in[11];
    const float* gnw_b = (const float*)d_in[12];
    const float* gn_w  = (const float*)d_in[13];
    const float* gn_b  = (const float*)d_in[14];
    const float* qw    = (const float*)d_in[15];
    const float* kw    = (const float*)d_in[16];
    const float* vw    = (const float*)d_in[17];

    float* ws = (float*)d_ws;
    const size_t N_BC56 = (size_t)B_ * C_ * HW_;   // 917504
    float* xh    = ws;
    float* xw    = xh + N_BC56;
    float* ah    = xw + N_BC56;
    float* aw    = ah + N_BC56;
    float* yy    = aw + N_BC56;                    // B*C*64 = 1048576
    float* stats = yy + (size_t)B_ * C_ * L2_;     // 64
    float* ca    = stats + 2 * B_;                 // 16384

    const int nbc = B_ * C_;   // 16384

    k_means<<<nbc, 256, 0, stream>>>(x, xh, xw);
    k_conv_gn_sig<<<B_ * 8, 256, 0, stream>>>(xh, xw, w3, b3, w5, b5, w7, b7, w9, b9,
                                              gnh_w, gnh_b, gnw_w, gnw_b, ah, aw);
    k_pool<<<nbc, 256, 0, stream>>>(x, ah, aw, yy);
    k_ystats<<<B_, 256, 0, stream>>>(yy, stats);
    k_attn<<<B_ * HEADS_, 256, 0, stream>>>(yy, stats, gn_w, gn_b, qw, kw, vw, ca);
    k_out<<<nbc, 256, 0, stream>>>(x, ah, aw, ca, (float*)d_out);
}

// Round 3
// 173.463 us; speedup vs baseline: 1.1909x; 1.1909x over previous
//
#include <hip/hip_runtime.h>
#include <hip/hip_bf16.h>
#include <math.h>

// Problem constants
#define B_     32
#define C_     512
#define HW_    56
#define PLANE  (HW_*HW_)     // 3136
#define PLANE4 (PLANE/4)     // 784
#define GC_    128
#define WIN_   7
#define L2_    64            // pooled spatial = 8*8
#define HEADS_ 8
#define HD_    64
#define EPS_   1e-5f

typedef float floatx4 __attribute__((ext_vector_type(4)));

// ---------------------------------------------------------------------------
// K1: per-(b,c) plane -> row means (over W) = x_h, col means (over H) = x_w
// ---------------------------------------------------------------------------
__global__ __launch_bounds__(256) void k_means(const float* __restrict__ x,
                                               float* __restrict__ xh,
                                               float* __restrict__ xw) {
    const int bc = blockIdx.x;
    const int t  = threadIdx.x;
    __shared__ float lds[PLANE];
    __shared__ float rp[224];
    __shared__ float cp[224];

    const float4* p4 = (const float4*)(x + (size_t)bc * PLANE);
    for (int f = t; f < PLANE4; f += 256) {
        float4 v = p4[f];
        int base = f * 4;
        lds[base]   = v.x; lds[base+1] = v.y;
        lds[base+2] = v.z; lds[base+3] = v.w;
    }
    __syncthreads();

    if (t < 224) {
        int r = t >> 2, q = t & 3;
        float s = 0.f;
        int base = r * HW_ + q * 14;
        #pragma unroll
        for (int i = 0; i < 14; i++) s += lds[base + i];
        rp[t] = s;
        float s2 = 0.f;
        int cbase = q * 14 * HW_ + r;
        #pragma unroll
        for (int i = 0; i < 14; i++) s2 += lds[cbase + i * HW_];
        cp[t] = s2;
    }
    __syncthreads();

    if (t < HW_) {
        float rs = rp[4*t] + rp[4*t+1] + rp[4*t+2] + rp[4*t+3];
        xh[(size_t)bc * HW_ + t] = rs * (1.0f / HW_);
        float cs = cp[4*t] + cp[4*t+1] + cp[4*t+2] + cp[4*t+3];
        xw[(size_t)bc * HW_ + t] = cs * (1.0f / HW_);
    }
}

// ---------------------------------------------------------------------------
// K2: per (b, group, {h|w}): depthwise conv1d (k=3/5/7/9) + bias, GroupNorm
// over (128 ch x 56), affine, sigmoid -> gate
// ---------------------------------------------------------------------------
__global__ __launch_bounds__(256) void k_conv_gn_sig(
    const float* __restrict__ xh, const float* __restrict__ xw,
    const float* __restrict__ w3, const float* __restrict__ b3,
    const float* __restrict__ w5, const float* __restrict__ b5,
    const float* __restrict__ w7, const float* __restrict__ b7,
    const float* __restrict__ w9, const float* __restrict__ b9,
    const float* __restrict__ gnh_w, const float* __restrict__ gnh_b,
    const float* __restrict__ gnw_w, const float* __restrict__ gnw_b,
    float* __restrict__ ah, float* __restrict__ aw) {

    const int blk = blockIdx.x;           // B*8
    const int b = blk >> 3;
    const int which = (blk & 7) >> 2;     // 0 = h, 1 = w
    const int g = blk & 3;
    const int t = threadIdx.x;

    const float* in  = (which ? xw : xh) + ((size_t)(b * C_ + g * GC_)) * HW_;
    float*       out = (which ? aw : ah) + ((size_t)(b * C_ + g * GC_)) * HW_;
    const float* gw  = (which ? gnw_w : gnh_w) + g * GC_;
    const float* gb  = (which ? gnw_b : gnh_b) + g * GC_;

    const float* wsel; const float* bsel; int ks;
    switch (g) {
        case 0:  wsel = w3; bsel = b3; ks = 3; break;
        case 1:  wsel = w5; bsel = b5; ks = 5; break;
        case 2:  wsel = w7; bsel = b7; ks = 7; break;
        default: wsel = w9; bsel = b9; ks = 9; break;
    }

    __shared__ float lin[GC_ * HW_];   // 28 KB
    __shared__ float wl[GC_ * 9];
    __shared__ float bl[GC_];
    __shared__ float red[10];

    for (int i = t; i < GC_ * HW_; i += 256) lin[i] = in[i];
    const int nw = GC_ * ks;
    for (int i = t; i < nw; i += 256) wl[i] = wsel[i];
    if (t < GC_) bl[t] = bsel[t];
    __syncthreads();

    const int k2 = ks >> 1;
    float acc[28];
    float s = 0.f, s2 = 0.f;
    #pragma unroll
    for (int k = 0; k < 28; k++) {
        int idx = t + k * 256;
        int c = idx / HW_, l = idx % HW_;
        float a = bl[c];
        for (int tt = 0; tt < ks; tt++) {
            int pos = l + tt - k2;
            if (pos >= 0 && pos < HW_) a += wl[c * ks + tt] * lin[c * HW_ + pos];
        }
        acc[k] = a;
        s += a; s2 += a * a;
    }

    #pragma unroll
    for (int o = 32; o > 0; o >>= 1) { s += __shfl_down(s, o); s2 += __shfl_down(s2, o); }
    int lane = t & 63, wid = t >> 6;
    if (lane == 0) { red[wid] = s; red[4 + wid] = s2; }
    __syncthreads();
    if (t == 0) {
        float S  = red[0] + red[1] + red[2] + red[3];
        float S2 = red[4] + red[5] + red[6] + red[7];
        float mean = S * (1.0f / (GC_ * HW_));
        float var  = S2 * (1.0f / (GC_ * HW_)) - mean * mean;
        red[8] = mean;
        red[9] = rsqrtf(var + EPS_);
    }
    __syncthreads();
    const float mean = red[8], rstd = red[9];

    #pragma unroll
    for (int k = 0; k < 28; k++) {
        int idx = t + k * 256;
        int c = idx / HW_;
        float v = (acc[k] - mean) * rstd * gw[c] + gb[c];
        out[idx] = 1.0f / (1.0f + expf(-v));
    }
}

// ---------------------------------------------------------------------------
// K3: per-(b,c): xg = x * ah[h] * aw[w]; 7x7 avg-pool -> y (B,C,8,8)
// ---------------------------------------------------------------------------
__global__ __launch_bounds__(256) void k_pool(const float* __restrict__ x,
                                              const float* __restrict__ ah,
                                              const float* __restrict__ aw,
                                              float* __restrict__ y) {
    const int bc = blockIdx.x;
    const int t  = threadIdx.x;
    __shared__ float lds[PLANE];
    __shared__ float a_h[HW_];
    __shared__ float a_w[HW_];

    if (t < HW_) {
        a_h[t] = ah[(size_t)bc * HW_ + t];
        a_w[t] = aw[(size_t)bc * HW_ + t];
    }
    __syncthreads();

    const float4* p4 = (const float4*)(x + (size_t)bc * PLANE);
    for (int f = t; f < PLANE4; f += 256) {
        float4 v = p4[f];
        int h = f / 14, jb = (f % 14) * 4;
        float m = a_h[h];
        int base = h * HW_ + jb;
        lds[base]   = v.x * m * a_w[jb];
        lds[base+1] = v.y * m * a_w[jb+1];
        lds[base+2] = v.z * m * a_w[jb+2];
        lds[base+3] = v.w * m * a_w[jb+3];
    }
    __syncthreads();

    if (t < L2_) {
        int hh = t >> 3, ww = t & 7;
        float s = 0.f;
        #pragma unroll
        for (int i = 0; i < WIN_; i++)
            #pragma unroll
            for (int j = 0; j < WIN_; j++)
                s += lds[(WIN_*hh + i) * HW_ + WIN_*ww + j];
        y[(size_t)bc * L2_ + t] = s * (1.0f / (WIN_*WIN_));
    }
}

// ---------------------------------------------------------------------------
// K4: per (b, head): per-batch GN stats (redundant per block, L2-hit) ->
// GN(affine) -> q,k,v; G = (q k^T)*0.125; softmax rows;
// ca[b, h*64+d] = sigmoid(sum_e p[d,e] * vbar[e]),  vbar[e] = mean_l v[e,l]
// ---------------------------------------------------------------------------
__global__ __launch_bounds__(256) void k_attn(const float* __restrict__ y,
                                              const float* __restrict__ gn_w,
                                              const float* __restrict__ gn_b,
                                              const float* __restrict__ qw,
                                              const float* __restrict__ kw,
                                              const float* __restrict__ vw,
                                              float* __restrict__ ca) {
    const int blk = blockIdx.x;     // B * HEADS
    const int b = blk >> 3, h = blk & 7;
    const int t = threadIdx.x;

    __shared__ float qs[HD_][68];
    __shared__ float ks_[HD_][68];
    __shared__ float att[HD_][68];
    __shared__ float vbar[HD_];
    __shared__ float red[10];

    // per-batch stats over y[b] (C*64 = 32768 floats), redundant per block
    {
        const float4* yb4 = (const float4*)(y + (size_t)b * (C_ * L2_));
        float s = 0.f, s2 = 0.f;
        for (int i = t; i < (C_ * L2_ / 4); i += 256) {
            float4 v = yb4[i];
            s  += v.x + v.y + v.z + v.w;
            s2 += v.x*v.x + v.y*v.y + v.z*v.z + v.w*v.w;
        }
        #pragma unroll
        for (int o = 32; o > 0; o >>= 1) { s += __shfl_down(s, o); s2 += __shfl_down(s2, o); }
        int lane = t & 63, wid = t >> 6;
        if (lane == 0) { red[wid] = s; red[4 + wid] = s2; }
        __syncthreads();
        if (t == 0) {
            float S  = red[0] + red[1] + red[2] + red[3];
            float S2 = red[4] + red[5] + red[6] + red[7];
            float mean = S * (1.0f / (C_ * L2_));
            float var  = S2 * (1.0f / (C_ * L2_)) - mean * mean;
            red[8] = mean;
            red[9] = rsqrtf(var + EPS_);
        }
        __syncthreads();
    }
    const float mu = red[8], rstd = red[9];

    const float4* yp4 = (const float4*)(y + ((size_t)(b * C_ + h * HD_)) * L2_);

    for (int f = t; f < 1024; f += 256) {
        int d = f >> 4, lb = (f & 15) << 2;
        int ch = h * HD_ + d;
        float gsc = gn_w[ch] * rstd;
        float gof = gn_b[ch] - mu * gsc;
        float qg = qw[ch], kg = kw[ch];
        float4 v = yp4[f];
        float y0 = v.x * gsc + gof, y1 = v.y * gsc + gof;
        float y2 = v.z * gsc + gof, y3 = v.w * gsc + gof;
        qs[d][lb]   = y0 * qg; qs[d][lb+1] = y1 * qg;
        qs[d][lb+2] = y2 * qg; qs[d][lb+3] = y3 * qg;
        ks_[d][lb]   = y0 * kg; ks_[d][lb+1] = y1 * kg;
        ks_[d][lb+2] = y2 * kg; ks_[d][lb+3] = y3 * kg;
        att[d][lb]   = y0; att[d][lb+1] = y1;
        att[d][lb+2] = y2; att[d][lb+3] = y3;
    }
    __syncthreads();

    if (t < HD_) {
        int ch = h * HD_ + t;
        float s = 0.f;
        #pragma unroll
        for (int l = 0; l < L2_; l++) s += att[t][l];
        vbar[t] = s * (1.0f / L2_) * vw[ch];
    }
    __syncthreads();

    // Gram: thread t -> row d = t>>2, cols e = (t&3) + 4*i, i in [0,16)
    const int d = t >> 2, eb = t & 3;
    float acc[16];
    #pragma unroll
    for (int i = 0; i < 16; i++) acc[i] = 0.f;
    #pragma unroll 4
    for (int lb = 0; lb < 16; lb++) {
        float4 qv = *(const float4*)&qs[d][lb * 4];
        #pragma unroll
        for (int i = 0; i < 16; i++) {
            float4 kv = *(const float4*)&ks_[eb + 4*i][lb * 4];
            acc[i] += qv.x * kv.x + qv.y * kv.y + qv.z * kv.z + qv.w * kv.w;
        }
    }
    __syncthreads();
    #pragma unroll
    for (int i = 0; i < 16; i++) att[d][eb + 4*i] = acc[i] * 0.125f;
    __syncthreads();

    {
        float m = -1e30f;
        #pragma unroll
        for (int i = 0; i < 16; i++) m = fmaxf(m, att[d][eb * 16 + i]);
        m = fmaxf(m, __shfl_xor(m, 1));
        m = fmaxf(m, __shfl_xor(m, 2));
        float s1 = 0.f, s2 = 0.f;
        #pragma unroll
        for (int i = 0; i < 16; i++) {
            int e = eb * 16 + i;
            float p = expf(att[d][e] - m);
            s1 += p;
            s2 += p * vbar[e];
        }
        s1 += __shfl_xor(s1, 1); s2 += __shfl_xor(s2, 1);
        s1 += __shfl_xor(s1, 2); s2 += __shfl_xor(s2, 2);
        if (eb == 0) {
            float o = s2 / s1;
            ca[(size_t)b * C_ + h * HD_ + d] = 1.0f / (1.0f + expf(-o));
        }
    }
}

// ---------------------------------------------------------------------------
// K5: out = x * ah[h] * aw[w] * ca[b,c] — pure grid-stride streaming,
// no LDS, no syncs; gates hit L1/L2; nontemporal output stores.
// ---------------------------------------------------------------------------
__global__ __launch_bounds__(256) void k_out(const float* __restrict__ x,
                                             const float* __restrict__ ah,
                                             const float* __restrict__ aw,
                                             const float* __restrict__ ca,
                                             float* __restrict__ out) {
    const unsigned total4 = (unsigned)B_ * C_ * PLANE4;  // 12,845,056
    const unsigned stride = gridDim.x * blockDim.x;
    const floatx4* px = (const floatx4*)x;
    floatx4*       po = (floatx4*)out;

    for (unsigned i = blockIdx.x * blockDim.x + threadIdx.x; i < total4; i += stride) {
        unsigned bc = i / PLANE4;            // const-div -> magic mul
        unsigned r  = i - bc * PLANE4;       // 0..783
        unsigned hh = r / 14;
        unsigned jb = (r - hh * 14) * 4;

        floatx4 v  = px[i];
        floatx4 w4 = *(const floatx4*)&aw[bc * HW_ + jb];
        float   m  = ca[bc] * ah[bc * HW_ + hh];
        v.x *= m * w4.x;
        v.y *= m * w4.y;
        v.z *= m * w4.z;
        v.w *= m * w4.w;
        __builtin_nontemporal_store(v, &po[i]);
    }
}

// ---------------------------------------------------------------------------
extern "C" void kernel_launch(void* const* d_in, const int* in_sizes, int n_in,
                              void* d_out, int out_size, void* d_ws, size_t ws_size,
                              hipStream_t stream) {
    const float* x     = (const float*)d_in[0];
    const float* w3    = (const float*)d_in[1];
    const float* b3    = (const float*)d_in[2];
    const float* w5    = (const float*)d_in[3];
    const float* b5    = (const float*)d_in[4];
    const float* w7    = (const float*)d_in[5];
    const float* b7    = (const float*)d_in[6];
    const float* w9    = (const float*)d_in[7];
    const float* b9    = (const float*)d_in[8];
    const float* gnh_w = (const float*)d_in[9];
    const float* gnh_b = (const float*)d_in[10];
    const float* gnw_w = (const float*)d_in[11];
    const float* gnw_b = (const float*)d_in[12];
    const float* gn_w  = (const float*)d_in[13];
    const float* gn_b  = (const float*)d_in[14];
    const float* qw    = (const float*)d_in[15];
    const float* kw    = (const float*)d_in[16];
    const float* vw    = (const float*)d_in[17];

    float* ws = (float*)d_ws;
    const size_t N_BC56 = (size_t)B_ * C_ * HW_;   // 917504
    float* xh    = ws;
    float* xw    = xh + N_BC56;
    float* ah    = xw + N_BC56;
    float* aw    = ah + N_BC56;
    float* yy    = aw + N_BC56;                    // B*C*64 = 1048576
    float* ca    = yy + (size_t)B_ * C_ * L2_;     // 16384

    const int nbc = B_ * C_;   // 16384

    k_means<<<nbc, 256, 0, stream>>>(x, xh, xw);
    k_conv_gn_sig<<<B_ * 8, 256, 0, stream>>>(xh, xw, w3, b3, w5, b5, w7, b7, w9, b9,
                                              gnh_w, gnh_b, gnw_w, gnw_b, ah, aw);
    k_pool<<<nbc, 256, 0, stream>>>(x, ah, aw, yy);
    k_attn<<<B_ * HEADS_, 256, 0, stream>>>(yy, gn_w, gn_b, qw, kw, vw, ca);
    k_out<<<2048, 256, 0, stream>>>(x, ah, aw, ca, (float*)d_out);
}